// Round 1
// baseline (1678.582 us; speedup 1.0000x reference)
//
#include <hip/hip_runtime.h>

#define TILE 64
#define KT 16

// ---------------------------------------------------------------------------
// Elementwise trace update: out = trace*decay + spikes  (vectorized float4)
// ---------------------------------------------------------------------------
__global__ __launch_bounds__(256) void trace_kernel(
    const float* __restrict__ spikes, const float* __restrict__ trace,
    float* __restrict__ out, int n4, float decay)
{
    int i = blockIdx.x * blockDim.x + threadIdx.x;
    if (i < n4) {
        float4 s = ((const float4*)spikes)[i];
        float4 tr = ((const float4*)trace)[i];
        float4 o;
        o.x = fmaf(tr.x, decay, s.x);
        o.y = fmaf(tr.y, decay, s.y);
        o.z = fmaf(tr.z, decay, s.z);
        o.w = fmaf(tr.w, decay, s.w);
        ((float4*)out)[i] = o;
    }
}

// ---------------------------------------------------------------------------
// Column-sum partials of post_spikes (B x POST), chunked over rows.
// partial[c*POST + p] = sum over rows of chunk c
// ---------------------------------------------------------------------------
__global__ __launch_bounds__(256) void colsum_partial_kernel(
    const float* __restrict__ post, float* __restrict__ partial,
    int POST, int rows)
{
    int p = blockIdx.x * blockDim.x + threadIdx.x;
    int c = blockIdx.y;
    const float* base = post + (size_t)c * rows * POST + p;
    float s = 0.f;
    for (int r = 0; r < rows; ++r) s += base[(size_t)r * POST];
    partial[(size_t)c * POST + p] = s;
}

__global__ __launch_bounds__(256) void rate_finalize_kernel(
    const float* __restrict__ partial, const float* __restrict__ rr,
    float* __restrict__ new_rate, int POST, int chunks, float invB)
{
    int p = blockIdx.x * blockDim.x + threadIdx.x;
    float s = 0.f;
    for (int c = 0; c < chunks; ++c) s += partial[(size_t)c * POST + p];
    new_rate[p] = rr[p] * 0.99f + 0.01f * (s * invB);
}

// ---------------------------------------------------------------------------
// Fused STDP weight update:
//   dw[p][q] = sum_{b} [ A+ * post_s[b][p] * (pre_tr[b][q]*dp)
//                       -A- * (post_tr[b][p]*dp) * pre_s[b][q] ] / B
// implemented as a single K=2B TN GEMM (both operands K-major, fully
// coalesced loads, direct LDS staging — no transpose needed).
//   new_w = clip(w + dw - HOMEO*(rr[p]-TARGET), 0, 1)
// 64x64 tile / block, 256 threads, 4x4 register micro-tile.
// ---------------------------------------------------------------------------
__global__ __launch_bounds__(256) void dw_weights_kernel(
    const float* __restrict__ post_spikes, // (B, POST)
    const float* __restrict__ post_trace,  // (B, POST)
    const float* __restrict__ pre_trace,   // (B, PRE)
    const float* __restrict__ pre_spikes,  // (B, PRE)
    const float* __restrict__ weights,     // (POST, PRE)
    const float* __restrict__ running_rate,// (POST)
    float* __restrict__ new_weights,       // (POST, PRE)
    int Bsz, int PRE, int POST)
{
    __shared__ float As[KT][TILE];  // As[k][p]  (bank 2-way aliased only: free)
    __shared__ float Bs[KT][TILE];  // Bs[k][q]
    const int p0 = blockIdx.y * TILE;
    const int q0 = blockIdx.x * TILE;
    const int t = threadIdx.x;
    const int col = t & 63;     // 0..63
    const int krow = t >> 6;    // 0..3 (wave-uniform)
    const int tx = t & 15;
    const int ty = t >> 4;      // 0..15
    const float dp = 0.95122942450071400910f;       // exp(-1/20)
    const float sPlus  = dp * (0.01f / (float)Bsz); // A+ * decay / B
    const float sMinus = -(0.01f / (float)Bsz);     // -A- / B

    float acc[4][4] = {};
    const int K = 2 * Bsz;
    for (int k0 = 0; k0 < K; k0 += KT) {
#pragma unroll
        for (int j = 0; j < 4; ++j) {
            int k = k0 + j * 4 + krow;
            float av, bv;
            if (k < Bsz) {
                av = post_spikes[(size_t)k * POST + p0 + col];
                bv = pre_trace  [(size_t)k * PRE  + q0 + col] * sPlus;
            } else {
                int kk = k - Bsz;
                av = post_trace [(size_t)kk * POST + p0 + col] * dp;
                bv = pre_spikes [(size_t)kk * PRE  + q0 + col] * sMinus;
            }
            As[j * 4 + krow][col] = av;
            Bs[j * 4 + krow][col] = bv;
        }
        __syncthreads();
#pragma unroll
        for (int k = 0; k < KT; ++k) {
            float4 a = *(const float4*)&As[k][ty * 4];
            float4 b = *(const float4*)&Bs[k][tx * 4];
            float av[4] = {a.x, a.y, a.z, a.w};
            float bv[4] = {b.x, b.y, b.z, b.w};
#pragma unroll
            for (int i = 0; i < 4; ++i)
#pragma unroll
                for (int j = 0; j < 4; ++j)
                    acc[i][j] = fmaf(av[i], bv[j], acc[i][j]);
        }
        __syncthreads();
    }

    // epilogue: w + dw + homeo, clipped
#pragma unroll
    for (int i = 0; i < 4; ++i) {
        int p = p0 + ty * 4 + i;
        float hp = -0.001f * (running_rate[p] - 0.1f);
        const float4 w = *(const float4*)&weights[(size_t)p * PRE + q0 + tx * 4];
        float4 o;
        o.x = fminf(fmaxf(w.x + acc[i][0] + hp, 0.f), 1.f);
        o.y = fminf(fmaxf(w.y + acc[i][1] + hp, 0.f), 1.f);
        o.z = fminf(fmaxf(w.z + acc[i][2] + hp, 0.f), 1.f);
        o.w = fminf(fmaxf(w.w + acc[i][3] + hp, 0.f), 1.f);
        *(float4*)&new_weights[(size_t)p * PRE + q0 + tx * 4] = o;
    }
}

// ---------------------------------------------------------------------------
// current[b][p] = sum_q pre_spikes[b][q] * new_w[p][q]   (NT GEMM)
// Both operands K-contiguous; transpose-stage into LDS with pad=+4 so the
// scatter writes are only 2-way bank aliased (free).
// ---------------------------------------------------------------------------
__global__ __launch_bounds__(256) void current_kernel(
    const float* __restrict__ pre_spikes, // (B, PRE)
    const float* __restrict__ W,          // (POST, PRE)
    float* __restrict__ current,          // (B, POST)
    int Bsz, int PRE, int POST)
{
    __shared__ float As[KT][TILE + 4];  // As[k][b]
    __shared__ float Bs[KT][TILE + 4];  // Bs[k][p]
    const int b0 = blockIdx.y * TILE;
    const int p0 = blockIdx.x * TILE;
    const int t = threadIdx.x;
    const int row = t >> 2;        // 0..63
    const int kq = (t & 3) * 4;    // 0,4,8,12
    const int tx = t & 15;
    const int ty = t >> 4;

    float acc[4][4] = {};
    for (int q0 = 0; q0 < PRE; q0 += KT) {
        float4 a = *(const float4*)&pre_spikes[(size_t)(b0 + row) * PRE + q0 + kq];
        float4 w = *(const float4*)&W[(size_t)(p0 + row) * PRE + q0 + kq];
        As[kq + 0][row] = a.x; As[kq + 1][row] = a.y;
        As[kq + 2][row] = a.z; As[kq + 3][row] = a.w;
        Bs[kq + 0][row] = w.x; Bs[kq + 1][row] = w.y;
        Bs[kq + 2][row] = w.z; Bs[kq + 3][row] = w.w;
        __syncthreads();
#pragma unroll
        for (int k = 0; k < KT; ++k) {
            float4 av4 = *(const float4*)&As[k][ty * 4];
            float4 bv4 = *(const float4*)&Bs[k][tx * 4];
            float av[4] = {av4.x, av4.y, av4.z, av4.w};
            float bv[4] = {bv4.x, bv4.y, bv4.z, bv4.w};
#pragma unroll
            for (int i = 0; i < 4; ++i)
#pragma unroll
                for (int j = 0; j < 4; ++j)
                    acc[i][j] = fmaf(av[i], bv[j], acc[i][j]);
        }
        __syncthreads();
    }

#pragma unroll
    for (int i = 0; i < 4; ++i) {
        int b = b0 + ty * 4 + i;
        float4 o = {acc[i][0], acc[i][1], acc[i][2], acc[i][3]};
        *(float4*)&current[(size_t)b * POST + p0 + tx * 4] = o;
    }
}

// ---------------------------------------------------------------------------
extern "C" void kernel_launch(void* const* d_in, const int* in_sizes, int n_in,
                              void* d_out, int out_size, void* d_ws, size_t ws_size,
                              hipStream_t stream)
{
    const float* pre_spikes   = (const float*)d_in[0];
    const float* post_spikes  = (const float*)d_in[1];
    const float* weights      = (const float*)d_in[2];
    const float* pre_trace    = (const float*)d_in[3];
    const float* post_trace   = (const float*)d_in[4];
    const float* running_rate = (const float*)d_in[5];

    const int POST = in_sizes[5];
    const int PRE  = in_sizes[2] / POST;
    const int Bsz  = in_sizes[0] / PRE;

    const size_t nCur   = (size_t)Bsz * POST;
    const size_t nW     = (size_t)POST * PRE;
    const size_t nPreT  = (size_t)Bsz * PRE;
    const size_t nPostT = (size_t)Bsz * POST;

    float* out_current    = (float*)d_out;
    float* out_weights    = out_current + nCur;
    float* out_pre_trace  = out_weights + nW;
    float* out_post_trace = out_pre_trace + nPreT;
    float* out_rate       = out_post_trace + nPostT;

    const float dp = 0.95122942450071400910f; // exp(-1/20)

    // 1) trace updates (elementwise)
    trace_kernel<<<(int)((nPreT / 4 + 255) / 256), 256, 0, stream>>>(
        pre_spikes, pre_trace, out_pre_trace, (int)(nPreT / 4), dp);
    trace_kernel<<<(int)((nPostT / 4 + 255) / 256), 256, 0, stream>>>(
        post_spikes, post_trace, out_post_trace, (int)(nPostT / 4), dp);

    // 2) rate EMA (split column sums into d_ws, then finalize)
    const int chunks = 8;
    float* partial = (float*)d_ws;
    colsum_partial_kernel<<<dim3(POST / 256, chunks), 256, 0, stream>>>(
        post_spikes, partial, POST, Bsz / chunks);
    rate_finalize_kernel<<<POST / 256, 256, 0, stream>>>(
        partial, running_rate, out_rate, POST, chunks, 1.0f / (float)Bsz);

    // 3) fused STDP dw GEMM (K = 2B) + homeo + clip -> new_weights
    dw_weights_kernel<<<dim3(PRE / TILE, POST / TILE), 256, 0, stream>>>(
        post_spikes, post_trace, pre_trace, pre_spikes, weights, running_rate,
        out_weights, Bsz, PRE, POST);

    // 4) current = pre_spikes @ new_weights^T  (depends on 3 via stream order)
    current_kernel<<<dim3(POST / TILE, Bsz / TILE), 256, 0, stream>>>(
        pre_spikes, out_weights, out_current, Bsz, PRE, POST);
}

// Round 2
// 471.669 us; speedup vs baseline: 3.5588x; 3.5588x over previous
//
#include <hip/hip_runtime.h>

typedef __attribute__((ext_vector_type(8))) short short8;
typedef __attribute__((ext_vector_type(4))) float floatx4;

#define LDS_PTR(x) ((__attribute__((address_space(3))) unsigned int*)(x))
#define GLB_PTR(x) ((const __attribute__((address_space(1))) unsigned int*)(x))

__device__ __forceinline__ unsigned short f2bf(float f) {
    unsigned int u = __float_as_uint(f);
    unsigned int r = (u + 0x7FFFu + ((u >> 16) & 1u)) >> 16;
    return (unsigned short)r;
}

// ---------------------------------------------------------------------------
// Elementwise trace update: out = trace*decay + spikes  (float4)
// ---------------------------------------------------------------------------
__global__ __launch_bounds__(256) void trace_kernel(
    const float* __restrict__ spikes, const float* __restrict__ trace,
    float* __restrict__ out, int n4, float decay)
{
    int i = blockIdx.x * blockDim.x + threadIdx.x;
    if (i < n4) {
        float4 s = ((const float4*)spikes)[i];
        float4 tr = ((const float4*)trace)[i];
        float4 o;
        o.x = fmaf(tr.x, decay, s.x);
        o.y = fmaf(tr.y, decay, s.y);
        o.z = fmaf(tr.z, decay, s.z);
        o.w = fmaf(tr.w, decay, s.w);
        ((float4*)out)[i] = o;
    }
}

// ---------------------------------------------------------------------------
// Rate EMA
// ---------------------------------------------------------------------------
__global__ __launch_bounds__(256) void colsum_partial_kernel(
    const float* __restrict__ post, float* __restrict__ partial,
    int POST, int rows)
{
    int p = blockIdx.x * blockDim.x + threadIdx.x;
    int c = blockIdx.y;
    const float* base = post + (size_t)c * rows * POST + p;
    float s = 0.f;
    for (int r = 0; r < rows; ++r) s += base[(size_t)r * POST];
    partial[(size_t)c * POST + p] = s;
}

__global__ __launch_bounds__(256) void rate_finalize_kernel(
    const float* __restrict__ partial, const float* __restrict__ rr,
    float* __restrict__ new_rate, int POST, int chunks, float invB)
{
    int p = blockIdx.x * blockDim.x + threadIdx.x;
    float s = 0.f;
    for (int c = 0; c < chunks; ++c) s += partial[(size_t)c * POST + p];
    new_rate[p] = rr[p] * 0.99f + 0.01f * (s * invB);
}

// ---------------------------------------------------------------------------
// Transpose + scale + cast to bf16:  dst[c][k_off + r] = scale * src[r][c]
// src: (R x C) fp32, dst rows have stride DS (bf16).  64x64 tiles.
// ---------------------------------------------------------------------------
__global__ __launch_bounds__(256) void transpose_cast_kernel(
    const float* __restrict__ src, unsigned short* __restrict__ dst,
    int C, int DS, int k_off, float scale)
{
    __shared__ float tile[64][65];
    const int t = threadIdx.x;
    const int r0 = blockIdx.y * 64, c0 = blockIdx.x * 64;
#pragma unroll
    for (int i = 0; i < 4; ++i) {
        int rl = (t >> 4) + i * 16;
        int cl = (t & 15) * 4;
        float4 v = *(const float4*)&src[(size_t)(r0 + rl) * C + c0 + cl];
        tile[rl][cl + 0] = v.x; tile[rl][cl + 1] = v.y;
        tile[rl][cl + 2] = v.z; tile[rl][cl + 3] = v.w;
    }
    __syncthreads();
#pragma unroll
    for (int i = 0; i < 4; ++i) {
        int cl = (t >> 4) + i * 16;
        int rl = (t & 15) * 4;
        ushort4 o;
        o.x = f2bf(tile[rl + 0][cl] * scale);
        o.y = f2bf(tile[rl + 1][cl] * scale);
        o.z = f2bf(tile[rl + 2][cl] * scale);
        o.w = f2bf(tile[rl + 3][cl] * scale);
        *(ushort4*)&dst[(size_t)(c0 + cl) * DS + k_off + r0 + rl] = o;
    }
}

// ---------------------------------------------------------------------------
// Elementwise fp32 -> bf16 cast (same layout)
// ---------------------------------------------------------------------------
__global__ __launch_bounds__(256) void cast_bf16_kernel(
    const float* __restrict__ src, unsigned short* __restrict__ dst, int n4)
{
    int i = blockIdx.x * blockDim.x + threadIdx.x;
    if (i < n4) {
        float4 v = ((const float4*)src)[i];
        ushort4 o = { f2bf(v.x), f2bf(v.y), f2bf(v.z), f2bf(v.w) };
        ((ushort4*)dst)[i] = o;
    }
}

// ---------------------------------------------------------------------------
// BT-form bf16 MFMA GEMM:  C[m][n] = sum_k A[m][k] * B[n][k]
// A: (M x K) bf16 row-major, B: (N x K) bf16 row-major.
// 256 threads = 4 waves (2x2), BK=32, 16x16x32 MFMA, global_load_lds w=16.
// WEPI: epilogue new_w = clip(acc + Wold + homeo(rr), 0, 1) -> fp32 + bf16.
// else: plain fp32 store.
// ---------------------------------------------------------------------------
template <int BM, int BN, bool WEPI>
__global__ __launch_bounds__(256) void mfma_gemm_bt(
    const unsigned short* __restrict__ A,
    const unsigned short* __restrict__ Bm,
    int K, int N,
    const float* __restrict__ Wold, const float* __restrict__ rr,
    float* __restrict__ outF, unsigned short* __restrict__ outBf)
{
    constexpr int BK = 32;
    constexpr int FI = BM / 32;   // fragments per wave in M
    constexpr int FJ = BN / 32;   // fragments per wave in N
    __shared__ unsigned short lA[BM * BK];
    __shared__ unsigned short lB[BN * BK];

    const int t = threadIdx.x;
    const int l = t & 63;
    const int w = t >> 6;
    const int wm = w >> 1, wn = w & 1;
    const int bm = blockIdx.y, bn = blockIdx.x;

    // staging addresses: thread t covers row t/4 (+64*i), k-chunk (t&3)*8
    const int srow = t >> 2;
    const int skc = (t & 3) * 8;

    floatx4 acc[FI][FJ] = {};

    for (int k0 = 0; k0 < K; k0 += BK) {
#pragma unroll
        for (int i = 0; i < BM / 64; ++i) {
            const unsigned short* gp =
                A + (size_t)(bm * BM + i * 64 + srow) * K + k0 + skc;
            __builtin_amdgcn_global_load_lds(GLB_PTR(gp),
                LDS_PTR(&lA[(i * 64 + srow) * BK + skc]), 16, 0, 0);
        }
#pragma unroll
        for (int i = 0; i < BN / 64; ++i) {
            const unsigned short* gp =
                Bm + (size_t)(bn * BN + i * 64 + srow) * K + k0 + skc;
            __builtin_amdgcn_global_load_lds(GLB_PTR(gp),
                LDS_PTR(&lB[(i * 64 + srow) * BK + skc]), 16, 0, 0);
        }
        __syncthreads();

        short8 af[FI], bf[FJ];
#pragma unroll
        for (int i = 0; i < FI; ++i)
            af[i] = *(const short8*)&lA[(wm * (BM / 2) + i * 16 + (l & 15)) * BK + (l >> 4) * 8];
#pragma unroll
        for (int j = 0; j < FJ; ++j)
            bf[j] = *(const short8*)&lB[(wn * (BN / 2) + j * 16 + (l & 15)) * BK + (l >> 4) * 8];
#pragma unroll
        for (int i = 0; i < FI; ++i)
#pragma unroll
            for (int j = 0; j < FJ; ++j)
                acc[i][j] = __builtin_amdgcn_mfma_f32_16x16x32_bf16(
                    af[i], bf[j], acc[i][j], 0, 0, 0);
        __syncthreads();
    }

    const int pBase = bm * BM + wm * (BM / 2);
    const int qBase = bn * BN + wn * (BN / 2);
#pragma unroll
    for (int i = 0; i < FI; ++i) {
#pragma unroll
        for (int r = 0; r < 4; ++r) {
            const int p = pBase + i * 16 + (l >> 4) * 4 + r;
            float hp = 0.f;
            if constexpr (WEPI) hp = -0.001f * (rr[p] - 0.1f);
#pragma unroll
            for (int j = 0; j < FJ; ++j) {
                const int q = qBase + j * 16 + (l & 15);
                const size_t idx = (size_t)p * N + q;
                float v = acc[i][j][r];
                if constexpr (WEPI) {
                    v = v + Wold[idx] + hp;
                    v = fminf(fmaxf(v, 0.f), 1.f);
                    outF[idx] = v;
                    outBf[idx] = f2bf(v);
                } else {
                    outF[idx] = v;
                }
            }
        }
    }
}

// ---------------------------------------------------------------------------
extern "C" void kernel_launch(void* const* d_in, const int* in_sizes, int n_in,
                              void* d_out, int out_size, void* d_ws, size_t ws_size,
                              hipStream_t stream)
{
    const float* pre_spikes   = (const float*)d_in[0];
    const float* post_spikes  = (const float*)d_in[1];
    const float* weights      = (const float*)d_in[2];
    const float* pre_trace    = (const float*)d_in[3];
    const float* post_trace   = (const float*)d_in[4];
    const float* running_rate = (const float*)d_in[5];

    const int POST = in_sizes[5];
    const int PRE  = in_sizes[2] / POST;
    const int Bsz  = in_sizes[0] / PRE;
    const int K2   = 2 * Bsz;

    const size_t nCur   = (size_t)Bsz * POST;
    const size_t nW     = (size_t)POST * PRE;
    const size_t nPreT  = (size_t)Bsz * PRE;
    const size_t nPostT = (size_t)Bsz * POST;

    float* out_current    = (float*)d_out;
    float* out_weights    = out_current + nCur;
    float* out_pre_trace  = out_weights + nW;
    float* out_post_trace = out_pre_trace + nPreT;
    float* out_rate       = out_post_trace + nPostT;

    // workspace layout (bf16 buffers)
    unsigned short* At    = (unsigned short*)d_ws;            // (POST x K2)
    unsigned short* Bt    = At + (size_t)POST * K2;           // (PRE  x K2)
    unsigned short* preBf = Bt + (size_t)PRE * K2;            // (B x PRE)
    unsigned short* wBf   = preBf + nPreT;                    // (POST x PRE)
    float* partial        = (float*)(wBf + nW);

    const float dp = 0.95122942450071400910f;     // exp(-1/20)
    const float sPlus  = dp * (0.01f / (float)Bsz);
    const float sMinus = -(0.01f / (float)Bsz);

    // 1) trace updates
    trace_kernel<<<(int)(nPreT / 4 / 256), 256, 0, stream>>>(
        pre_spikes, pre_trace, out_pre_trace, (int)(nPreT / 4), dp);
    trace_kernel<<<(int)(nPostT / 4 / 256), 256, 0, stream>>>(
        post_spikes, post_trace, out_post_trace, (int)(nPostT / 4), dp);

    // 2) rate EMA
    const int chunks = 8;
    colsum_partial_kernel<<<dim3(POST / 256, chunks), 256, 0, stream>>>(
        post_spikes, partial, POST, Bsz / chunks);
    rate_finalize_kernel<<<POST / 256, 256, 0, stream>>>(
        partial, running_rate, out_rate, POST, chunks, 1.0f / (float)Bsz);

    // 3) build bf16 K-contiguous operands
    // At[p][k] = k<B ? post_spikes[k][p] : dp*post_trace[k-B][p]
    transpose_cast_kernel<<<dim3(POST / 64, Bsz / 64), 256, 0, stream>>>(
        post_spikes, At, POST, K2, 0, 1.0f);
    transpose_cast_kernel<<<dim3(POST / 64, Bsz / 64), 256, 0, stream>>>(
        post_trace, At, POST, K2, Bsz, dp);
    // Bt[q][k] = k<B ? sPlus*pre_trace[k][q] : sMinus*pre_spikes[k-B][q]
    transpose_cast_kernel<<<dim3(PRE / 64, Bsz / 64), 256, 0, stream>>>(
        pre_trace, Bt, PRE, K2, 0, sPlus);
    transpose_cast_kernel<<<dim3(PRE / 64, Bsz / 64), 256, 0, stream>>>(
        pre_spikes, Bt, PRE, K2, Bsz, sMinus);
    // preBf = bf16(pre_spikes), native (B x PRE) layout
    cast_bf16_kernel<<<(int)(nPreT / 4 / 256), 256, 0, stream>>>(
        pre_spikes, preBf, (int)(nPreT / 4));

    // 4) dw GEMM (M=POST, N=PRE, K=2B) + fused w/homeo/clip epilogue
    mfma_gemm_bt<128, 128, true><<<dim3(PRE / 128, POST / 128), 256, 0, stream>>>(
        At, Bt, K2, PRE, weights, running_rate, out_weights, wBf);

    // 5) current GEMM (M=B, N=POST, K=PRE): pre_spikes @ new_w^T
    mfma_gemm_bt<64, 128, false><<<dim3(POST / 128, Bsz / 64), 256, 0, stream>>>(
        preBf, wBf, PRE, POST, nullptr, nullptr, out_current, nullptr);
}

// Round 3
// 402.379 us; speedup vs baseline: 4.1716x; 1.1722x over previous
//
#include <hip/hip_runtime.h>

typedef __attribute__((ext_vector_type(8))) short short8;
typedef __attribute__((ext_vector_type(4))) float floatx4;

#define LDS_PTR(x) ((__attribute__((address_space(3))) unsigned int*)(x))
#define GLB_PTR(x) ((const __attribute__((address_space(1))) unsigned int*)(x))

__device__ __forceinline__ unsigned short f2bf(float f) {
    unsigned int u = __float_as_uint(f);
    unsigned int r = (u + 0x7FFFu + ((u >> 16) & 1u)) >> 16;
    return (unsigned short)r;
}
__device__ __forceinline__ float bf2f(unsigned short u) {
    return __uint_as_float(((unsigned int)u) << 16);
}

// ---------------------------------------------------------------------------
// Fused post-side prep (one read of post_spikes & post_trace):
//   out_post_trace[b][p] = S + dp*T            (native, float4)
//   At[p][k]   = bf16(S^T)        k in [0,B)
//   At[p][B+k] = bf16(dp * T^T)
// ---------------------------------------------------------------------------
__global__ __launch_bounds__(256) void prep_post_kernel(
    const float* __restrict__ S, const float* __restrict__ T,
    float* __restrict__ traceOut, unsigned short* __restrict__ At,
    int C, int K2, int Bsz, float dp)
{
    __shared__ float sT[64][65];
    __shared__ float tT[64][65];
    const int t = threadIdx.x;
    const int r0 = blockIdx.y * 64, c0 = blockIdx.x * 64;
#pragma unroll
    for (int i = 0; i < 4; ++i) {
        int rl = (t >> 4) + i * 16;
        int cl = (t & 15) * 4;
        size_t g = (size_t)(r0 + rl) * C + c0 + cl;
        float4 s4 = *(const float4*)&S[g];
        float4 t4 = *(const float4*)&T[g];
        float4 o;
        o.x = fmaf(t4.x, dp, s4.x); o.y = fmaf(t4.y, dp, s4.y);
        o.z = fmaf(t4.z, dp, s4.z); o.w = fmaf(t4.w, dp, s4.w);
        *(float4*)&traceOut[g] = o;
        sT[rl][cl + 0] = s4.x; sT[rl][cl + 1] = s4.y;
        sT[rl][cl + 2] = s4.z; sT[rl][cl + 3] = s4.w;
        tT[rl][cl + 0] = t4.x; tT[rl][cl + 1] = t4.y;
        tT[rl][cl + 2] = t4.z; tT[rl][cl + 3] = t4.w;
    }
    __syncthreads();
#pragma unroll
    for (int i = 0; i < 4; ++i) {
        int cl = (t >> 4) + i * 16;
        int rl = (t & 15) * 4;
        ushort4 a, b;
        a.x = f2bf(sT[rl + 0][cl]); a.y = f2bf(sT[rl + 1][cl]);
        a.z = f2bf(sT[rl + 2][cl]); a.w = f2bf(sT[rl + 3][cl]);
        b.x = f2bf(tT[rl + 0][cl] * dp); b.y = f2bf(tT[rl + 1][cl] * dp);
        b.z = f2bf(tT[rl + 2][cl] * dp); b.w = f2bf(tT[rl + 3][cl] * dp);
        *(ushort4*)&At[(size_t)(c0 + cl) * K2 + r0 + rl] = a;
        *(ushort4*)&At[(size_t)(c0 + cl) * K2 + Bsz + r0 + rl] = b;
    }
}

// ---------------------------------------------------------------------------
// Fused pre-side prep (one read of pre_spikes & pre_trace):
//   out_pre_trace = S + dp*T (native)
//   preBf[b][q]   = bf16(S)  (native)
//   Bt[q][k]   = bf16(sPlus  * T^T)   k in [0,B)
//   Bt[q][B+k] = bf16(sMinus * S^T)
// ---------------------------------------------------------------------------
__global__ __launch_bounds__(256) void prep_pre_kernel(
    const float* __restrict__ S, const float* __restrict__ T,
    float* __restrict__ traceOut, unsigned short* __restrict__ Bt,
    unsigned short* __restrict__ preBf,
    int C, int K2, int Bsz, float dp, float sPlus, float sMinus)
{
    __shared__ float sT[64][65];
    __shared__ float tT[64][65];
    const int t = threadIdx.x;
    const int r0 = blockIdx.y * 64, c0 = blockIdx.x * 64;
#pragma unroll
    for (int i = 0; i < 4; ++i) {
        int rl = (t >> 4) + i * 16;
        int cl = (t & 15) * 4;
        size_t g = (size_t)(r0 + rl) * C + c0 + cl;
        float4 s4 = *(const float4*)&S[g];
        float4 t4 = *(const float4*)&T[g];
        float4 o;
        o.x = fmaf(t4.x, dp, s4.x); o.y = fmaf(t4.y, dp, s4.y);
        o.z = fmaf(t4.z, dp, s4.z); o.w = fmaf(t4.w, dp, s4.w);
        *(float4*)&traceOut[g] = o;
        ushort4 pb = { f2bf(s4.x), f2bf(s4.y), f2bf(s4.z), f2bf(s4.w) };
        *(ushort4*)&preBf[g] = pb;
        sT[rl][cl + 0] = s4.x; sT[rl][cl + 1] = s4.y;
        sT[rl][cl + 2] = s4.z; sT[rl][cl + 3] = s4.w;
        tT[rl][cl + 0] = t4.x; tT[rl][cl + 1] = t4.y;
        tT[rl][cl + 2] = t4.z; tT[rl][cl + 3] = t4.w;
    }
    __syncthreads();
#pragma unroll
    for (int i = 0; i < 4; ++i) {
        int cl = (t >> 4) + i * 16;
        int rl = (t & 15) * 4;
        ushort4 a, b;
        a.x = f2bf(tT[rl + 0][cl] * sPlus); a.y = f2bf(tT[rl + 1][cl] * sPlus);
        a.z = f2bf(tT[rl + 2][cl] * sPlus); a.w = f2bf(tT[rl + 3][cl] * sPlus);
        b.x = f2bf(sT[rl + 0][cl] * sMinus); b.y = f2bf(sT[rl + 1][cl] * sMinus);
        b.z = f2bf(sT[rl + 2][cl] * sMinus); b.w = f2bf(sT[rl + 3][cl] * sMinus);
        *(ushort4*)&Bt[(size_t)(c0 + cl) * K2 + r0 + rl] = a;
        *(ushort4*)&Bt[(size_t)(c0 + cl) * K2 + Bsz + r0 + rl] = b;
    }
}

// ---------------------------------------------------------------------------
// Rate EMA from transposed bf16 post_spikes (At rows, contiguous in k).
// One wave per post-neuron row; shuffle reduction.
// ---------------------------------------------------------------------------
__global__ __launch_bounds__(256) void rate_kernel(
    const unsigned short* __restrict__ At, const float* __restrict__ rr,
    float* __restrict__ new_rate, int K2, int Bsz)
{
    const int w = threadIdx.x >> 6, l = threadIdx.x & 63;
    const int p = blockIdx.x * 4 + w;
    const unsigned short* row = At + (size_t)p * K2;
    float s = 0.f;
    for (int k = l * 8; k < Bsz; k += 512) {
        short8 v = *(const short8*)&row[k];
#pragma unroll
        for (int j = 0; j < 8; ++j) s += bf2f((unsigned short)v[j]);
    }
#pragma unroll
    for (int off = 32; off > 0; off >>= 1) s += __shfl_xor(s, off, 64);
    if (l == 0)
        new_rate[p] = rr[p] * 0.99f + 0.01f * (s / (float)Bsz);
}

// ---------------------------------------------------------------------------
// BT-form bf16 MFMA GEMM with XOR-swizzled LDS (conflict-free b128 reads):
//   C[m][n] = sum_k A[m][k]*B[n][k];  A:(MxK), B:(NxK) bf16 row-major.
// Logical k-chunk c of row r is stored at chunk c ^ ((r>>1)&3).
// ---------------------------------------------------------------------------
template <int BM, int BN, bool WEPI>
__global__ __launch_bounds__(256) void mfma_gemm_bt(
    const unsigned short* __restrict__ A,
    const unsigned short* __restrict__ Bm,
    int K, int N,
    const float* __restrict__ Wold, const float* __restrict__ rr,
    float* __restrict__ outF, unsigned short* __restrict__ outBf)
{
    constexpr int BK = 32;
    constexpr int FI = BM / 32;
    constexpr int FJ = BN / 32;
    __shared__ unsigned short lA[BM * BK];
    __shared__ unsigned short lB[BN * BK];

    const int t = threadIdx.x;
    const int l = t & 63;
    const int w = t >> 6;
    const int wm = w >> 1, wn = w & 1;
    const int bm = blockIdx.y, bn = blockIdx.x;

    // staging: thread t fills LDS bytes [t*16, t*16+16) (lane-contiguous),
    // sourcing the swizzled global chunk.
    const int srow = t >> 2;
    const int sc = t & 3;                         // stored chunk
    const int gc = sc ^ ((srow >> 1) & 3);        // logical (global) chunk
    const int skc = sc * 8;                       // stored elem offset
    const int gkc = gc * 8;                       // global elem offset

    floatx4 acc[FI][FJ] = {};

    for (int k0 = 0; k0 < K; k0 += BK) {
#pragma unroll
        for (int i = 0; i < BM / 64; ++i) {
            const unsigned short* gp =
                A + (size_t)(bm * BM + i * 64 + srow) * K + k0 + gkc;
            __builtin_amdgcn_global_load_lds(GLB_PTR(gp),
                LDS_PTR(&lA[(i * 64 + srow) * BK + skc]), 16, 0, 0);
        }
#pragma unroll
        for (int i = 0; i < BN / 64; ++i) {
            const unsigned short* gp =
                Bm + (size_t)(bn * BN + i * 64 + srow) * K + k0 + gkc;
            __builtin_amdgcn_global_load_lds(GLB_PTR(gp),
                LDS_PTR(&lB[(i * 64 + srow) * BK + skc]), 16, 0, 0);
        }
        __syncthreads();

        const int q = l >> 4;                     // logical k-chunk for frags
        short8 af[FI], bf[FJ];
#pragma unroll
        for (int i = 0; i < FI; ++i) {
            int ra = wm * (BM / 2) + i * 16 + (l & 15);
            af[i] = *(const short8*)&lA[ra * BK + ((q ^ ((ra >> 1) & 3)) * 8)];
        }
#pragma unroll
        for (int j = 0; j < FJ; ++j) {
            int rb = wn * (BN / 2) + j * 16 + (l & 15);
            bf[j] = *(const short8*)&lB[rb * BK + ((q ^ ((rb >> 1) & 3)) * 8)];
        }
#pragma unroll
        for (int i = 0; i < FI; ++i)
#pragma unroll
            for (int j = 0; j < FJ; ++j)
                acc[i][j] = __builtin_amdgcn_mfma_f32_16x16x32_bf16(
                    af[i], bf[j], acc[i][j], 0, 0, 0);
        __syncthreads();
    }

    const int pBase = bm * BM + wm * (BM / 2);
    const int qBase = bn * BN + wn * (BN / 2);
#pragma unroll
    for (int i = 0; i < FI; ++i) {
#pragma unroll
        for (int r = 0; r < 4; ++r) {
            const int p = pBase + i * 16 + (l >> 4) * 4 + r;
            float hp = 0.f;
            if constexpr (WEPI) hp = -0.001f * (rr[p] - 0.1f);
#pragma unroll
            for (int j = 0; j < FJ; ++j) {
                const int q = qBase + j * 16 + (l & 15);
                const size_t idx = (size_t)p * N + q;
                float v = acc[i][j][r];
                if constexpr (WEPI) {
                    v = v + Wold[idx] + hp;
                    v = fminf(fmaxf(v, 0.f), 1.f);
                    outF[idx] = v;
                    outBf[idx] = f2bf(v);
                } else {
                    outF[idx] = v;
                }
            }
        }
    }
}

// ---------------------------------------------------------------------------
extern "C" void kernel_launch(void* const* d_in, const int* in_sizes, int n_in,
                              void* d_out, int out_size, void* d_ws, size_t ws_size,
                              hipStream_t stream)
{
    const float* pre_spikes   = (const float*)d_in[0];
    const float* post_spikes  = (const float*)d_in[1];
    const float* weights      = (const float*)d_in[2];
    const float* pre_trace    = (const float*)d_in[3];
    const float* post_trace   = (const float*)d_in[4];
    const float* running_rate = (const float*)d_in[5];

    const int POST = in_sizes[5];
    const int PRE  = in_sizes[2] / POST;
    const int Bsz  = in_sizes[0] / PRE;
    const int K2   = 2 * Bsz;

    const size_t nCur   = (size_t)Bsz * POST;
    const size_t nW     = (size_t)POST * PRE;
    const size_t nPreT  = (size_t)Bsz * PRE;
    const size_t nPostT = (size_t)Bsz * POST;

    float* out_current    = (float*)d_out;
    float* out_weights    = out_current + nCur;
    float* out_pre_trace  = out_weights + nW;
    float* out_post_trace = out_pre_trace + nPreT;
    float* out_rate       = out_post_trace + nPostT;

    unsigned short* At    = (unsigned short*)d_ws;   // (POST x K2)
    unsigned short* Bt    = At + (size_t)POST * K2;  // (PRE  x K2)
    unsigned short* preBf = Bt + (size_t)PRE * K2;   // (B x PRE)
    unsigned short* wBf   = preBf + nPreT;           // (POST x PRE)

    const float dp = 0.95122942450071400910f;        // exp(-1/20)
    const float sPlus  = dp * (0.01f / (float)Bsz);
    const float sMinus = -(0.01f / (float)Bsz);

    // 1) fused prep: traces out + bf16 GEMM operands (single read per input)
    prep_post_kernel<<<dim3(POST / 64, Bsz / 64), 256, 0, stream>>>(
        post_spikes, post_trace, out_post_trace, At, POST, K2, Bsz, dp);
    prep_pre_kernel<<<dim3(PRE / 64, Bsz / 64), 256, 0, stream>>>(
        pre_spikes, pre_trace, out_pre_trace, Bt, preBf, PRE, K2, Bsz,
        dp, sPlus, sMinus);

    // 2) rate EMA from At (contiguous bf16 rows)
    rate_kernel<<<POST / 4, 256, 0, stream>>>(
        At, running_rate, out_rate, K2, Bsz);

    // 3) dw GEMM (M=POST, N=PRE, K=2B) + fused w/homeo/clip epilogue
    mfma_gemm_bt<128, 128, true><<<dim3(PRE / 128, POST / 128), 256, 0, stream>>>(
        At, Bt, K2, PRE, weights, running_rate, out_weights, wBf);

    // 4) current GEMM (M=B, N=POST, K=PRE): pre_spikes @ new_w^T
    mfma_gemm_bt<64, 128, false><<<dim3(POST / 128, Bsz / 64), 256, 0, stream>>>(
        preBf, wBf, PRE, POST, nullptr, nullptr, out_current, nullptr);
}

// Round 4
// 346.112 us; speedup vs baseline: 4.8498x; 1.1626x over previous
//
#include <hip/hip_runtime.h>
#include <hip/hip_fp8.h>

typedef __attribute__((ext_vector_type(8))) short short8;
typedef __attribute__((ext_vector_type(4))) float floatx4;
typedef __attribute__((ext_vector_type(8))) int int8v;
typedef __attribute__((ext_vector_type(4))) int int4v;

#define LDS_PTR(x) ((__attribute__((address_space(3))) unsigned int*)(x))
#define GLB_PTR(x) ((const __attribute__((address_space(1))) unsigned int*)(x))

__device__ __forceinline__ unsigned short f2bf(float f) {
    unsigned int u = __float_as_uint(f);
    unsigned int r = (u + 0x7FFFu + ((u >> 16) & 1u)) >> 16;
    return (unsigned short)r;
}
__device__ __forceinline__ unsigned char f2fp8(float f) {
    __hip_fp8_e4m3 v(f);
    return (unsigned char)v.__x;
}
__device__ __forceinline__ float fp82f(unsigned int u) {
    __hip_fp8_e4m3 v;
    v.__x = (__hip_fp8_storage_t)(u & 0xFF);
    return (float)v;
}

// ---------------------------------------------------------------------------
// Fused post-side prep (one read of post_spikes & post_trace):
//   out_post_trace = S + dp*T (fp32, native)
//   At[p][k]   = fp8(S^T)   k in [0,B)      (RAW spikes)
//   At[p][B+k] = fp8(T^T)                   (RAW trace — dp folded into s)
// ---------------------------------------------------------------------------
__global__ __launch_bounds__(256) void prep_post_kernel(
    const float* __restrict__ S, const float* __restrict__ T,
    float* __restrict__ traceOut, unsigned char* __restrict__ At,
    int C, int K2, int Bsz, float dp)
{
    __shared__ float sT[64][65];
    __shared__ float tT[64][65];
    const int t = threadIdx.x;
    const int r0 = blockIdx.y * 64, c0 = blockIdx.x * 64;
#pragma unroll
    for (int i = 0; i < 4; ++i) {
        int rl = (t >> 4) + i * 16;
        int cl = (t & 15) * 4;
        size_t g = (size_t)(r0 + rl) * C + c0 + cl;
        float4 s4 = *(const float4*)&S[g];
        float4 t4 = *(const float4*)&T[g];
        float4 o;
        o.x = fmaf(t4.x, dp, s4.x); o.y = fmaf(t4.y, dp, s4.y);
        o.z = fmaf(t4.z, dp, s4.z); o.w = fmaf(t4.w, dp, s4.w);
        *(float4*)&traceOut[g] = o;
        sT[rl][cl + 0] = s4.x; sT[rl][cl + 1] = s4.y;
        sT[rl][cl + 2] = s4.z; sT[rl][cl + 3] = s4.w;
        tT[rl][cl + 0] = t4.x; tT[rl][cl + 1] = t4.y;
        tT[rl][cl + 2] = t4.z; tT[rl][cl + 3] = t4.w;
    }
    __syncthreads();
#pragma unroll
    for (int i = 0; i < 4; ++i) {
        int cl = (t >> 4) + i * 16;
        int rl = (t & 15) * 4;
        uchar4 a, b;
        a.x = f2fp8(sT[rl + 0][cl]); a.y = f2fp8(sT[rl + 1][cl]);
        a.z = f2fp8(sT[rl + 2][cl]); a.w = f2fp8(sT[rl + 3][cl]);
        b.x = f2fp8(tT[rl + 0][cl]); b.y = f2fp8(tT[rl + 1][cl]);
        b.z = f2fp8(tT[rl + 2][cl]); b.w = f2fp8(tT[rl + 3][cl]);
        *(uchar4*)&At[(size_t)(c0 + cl) * K2 + r0 + rl] = a;
        *(uchar4*)&At[(size_t)(c0 + cl) * K2 + Bsz + r0 + rl] = b;
    }
}

// ---------------------------------------------------------------------------
// Fused pre-side prep:
//   out_pre_trace = S + dp*T (fp32, native);  preBf = bf16(S) (native)
//   Bt[q][k]   = fp8(T^T)       (RAW pre_trace)
//   Bt[q][B+k] = fp8(-S^T)      (negated pre_spikes — sign folded)
// ---------------------------------------------------------------------------
__global__ __launch_bounds__(256) void prep_pre_kernel(
    const float* __restrict__ S, const float* __restrict__ T,
    float* __restrict__ traceOut, unsigned char* __restrict__ Bt,
    unsigned short* __restrict__ preBf,
    int C, int K2, int Bsz, float dp)
{
    __shared__ float sT[64][65];
    __shared__ float tT[64][65];
    const int t = threadIdx.x;
    const int r0 = blockIdx.y * 64, c0 = blockIdx.x * 64;
#pragma unroll
    for (int i = 0; i < 4; ++i) {
        int rl = (t >> 4) + i * 16;
        int cl = (t & 15) * 4;
        size_t g = (size_t)(r0 + rl) * C + c0 + cl;
        float4 s4 = *(const float4*)&S[g];
        float4 t4 = *(const float4*)&T[g];
        float4 o;
        o.x = fmaf(t4.x, dp, s4.x); o.y = fmaf(t4.y, dp, s4.y);
        o.z = fmaf(t4.z, dp, s4.z); o.w = fmaf(t4.w, dp, s4.w);
        *(float4*)&traceOut[g] = o;
        ushort4 pb = { f2bf(s4.x), f2bf(s4.y), f2bf(s4.z), f2bf(s4.w) };
        *(ushort4*)&preBf[g] = pb;
        sT[rl][cl + 0] = s4.x; sT[rl][cl + 1] = s4.y;
        sT[rl][cl + 2] = s4.z; sT[rl][cl + 3] = s4.w;
        tT[rl][cl + 0] = t4.x; tT[rl][cl + 1] = t4.y;
        tT[rl][cl + 2] = t4.z; tT[rl][cl + 3] = t4.w;
    }
    __syncthreads();
#pragma unroll
    for (int i = 0; i < 4; ++i) {
        int cl = (t >> 4) + i * 16;
        int rl = (t & 15) * 4;
        uchar4 a, b;
        a.x = f2fp8(tT[rl + 0][cl]); a.y = f2fp8(tT[rl + 1][cl]);
        a.z = f2fp8(tT[rl + 2][cl]); a.w = f2fp8(tT[rl + 3][cl]);
        b.x = f2fp8(-sT[rl + 0][cl]); b.y = f2fp8(-sT[rl + 1][cl]);
        b.z = f2fp8(-sT[rl + 2][cl]); b.w = f2fp8(-sT[rl + 3][cl]);
        *(uchar4*)&Bt[(size_t)(c0 + cl) * K2 + r0 + rl] = a;
        *(uchar4*)&Bt[(size_t)(c0 + cl) * K2 + Bsz + r0 + rl] = b;
    }
}

// ---------------------------------------------------------------------------
// Rate EMA from fp8-transposed post_spikes rows (At, k-contiguous).
// One wave per post neuron; each lane decodes 16 bytes; shuffle reduce.
// ---------------------------------------------------------------------------
__global__ __launch_bounds__(256) void rate_kernel(
    const unsigned char* __restrict__ At, const float* __restrict__ rr,
    float* __restrict__ new_rate, int K2, int Bsz)
{
    const int w = threadIdx.x >> 6, l = threadIdx.x & 63;
    const int p = blockIdx.x * 4 + w;
    const unsigned char* row = At + (size_t)p * K2;
    float s = 0.f;
    for (int k = l * 16; k < Bsz; k += 1024) {
        int4v v = *(const int4v*)&row[k];
#pragma unroll
        for (int wd = 0; wd < 4; ++wd) {
            unsigned int u = (unsigned int)v[wd];
            s += fp82f(u) + fp82f(u >> 8) + fp82f(u >> 16) + fp82f(u >> 24);
        }
    }
#pragma unroll
    for (int off = 32; off > 0; off >>= 1) s += __shfl_xor(s, off, 64);
    if (l == 0)
        new_rate[p] = rr[p] * 0.99f + 0.01f * (s / (float)Bsz);
}

// ---------------------------------------------------------------------------
// MX-fp8 dw GEMM: dw[p][q] = s * sum_k A[p][k]*B[q][k]  (both K-major fp8)
// 128x128 tile, BK=128, mfma_scale_f32_16x16x128_f8f6f4, unit e8m0 scales.
// XOR-swizzled LDS (16B sub-chunk ^ (row&7)) -> conflict-free b128 reads.
// Epilogue: new_w = clip(s*acc + Wold + homeo(rr), 0, 1) -> fp32 + bf16.
// ---------------------------------------------------------------------------
__global__ __launch_bounds__(256) void dw_fp8_kernel(
    const unsigned char* __restrict__ A, const unsigned char* __restrict__ B,
    int K, int N, float s,
    const float* __restrict__ Wold, const float* __restrict__ rr,
    float* __restrict__ outF, unsigned short* __restrict__ outBf)
{
    constexpr int BM = 128, BN = 128, BK = 128;
    __shared__ unsigned char lA[BM * BK];
    __shared__ unsigned char lB[BN * BK];

    const int t = threadIdx.x;
    const int l = t & 63;
    const int w = t >> 6;
    const int wm = w >> 1, wn = w & 1;
    const int bm = blockIdx.y, bn = blockIdx.x;

    floatx4 acc[4][4] = {};

    for (int k0 = 0; k0 < K; k0 += BK) {
#pragma unroll
        for (int i = 0; i < 4; ++i) {
            int ci = i * 256 + t;            // 16B chunk index (lane-linear)
            int r = ci >> 3, sc = ci & 7;
            int g = sc ^ (r & 7);            // swizzled source sub-chunk
            const unsigned char* gpA = A + (size_t)(bm * BM + r) * K + k0 + g * 16;
            __builtin_amdgcn_global_load_lds(GLB_PTR(gpA),
                LDS_PTR(&lA[ci * 16]), 16, 0, 0);
            const unsigned char* gpB = B + (size_t)(bn * BN + r) * K + k0 + g * 16;
            __builtin_amdgcn_global_load_lds(GLB_PTR(gpB),
                LDS_PTR(&lB[ci * 16]), 16, 0, 0);
        }
        __syncthreads();

        const int c = l >> 4;      // k-quad: covers k bytes [c*32, c*32+32)
        const int m = l & 15;
        int8v af[4], bf[4];
#pragma unroll
        for (int i = 0; i < 4; ++i) {
            int ra = wm * 64 + i * 16 + m;
            int s0 = (2 * c) ^ (ra & 7), s1 = (2 * c + 1) ^ (ra & 7);
            int4v lo = *(const int4v*)&lA[ra * BK + s0 * 16];
            int4v hi = *(const int4v*)&lA[ra * BK + s1 * 16];
            af[i][0] = lo[0]; af[i][1] = lo[1]; af[i][2] = lo[2]; af[i][3] = lo[3];
            af[i][4] = hi[0]; af[i][5] = hi[1]; af[i][6] = hi[2]; af[i][7] = hi[3];
        }
#pragma unroll
        for (int j = 0; j < 4; ++j) {
            int rb = wn * 64 + j * 16 + m;
            int s0 = (2 * c) ^ (rb & 7), s1 = (2 * c + 1) ^ (rb & 7);
            int4v lo = *(const int4v*)&lB[rb * BK + s0 * 16];
            int4v hi = *(const int4v*)&lB[rb * BK + s1 * 16];
            bf[j][0] = lo[0]; bf[j][1] = lo[1]; bf[j][2] = lo[2]; bf[j][3] = lo[3];
            bf[j][4] = hi[0]; bf[j][5] = hi[1]; bf[j][6] = hi[2]; bf[j][7] = hi[3];
        }
#pragma unroll
        for (int i = 0; i < 4; ++i)
#pragma unroll
            for (int j = 0; j < 4; ++j)
                acc[i][j] = __builtin_amdgcn_mfma_scale_f32_16x16x128_f8f6f4(
                    af[i], bf[j], acc[i][j], 0, 0, 0, 0x7f, 0, 0x7f);
        __syncthreads();
    }

    const int pBase = bm * BM + wm * 64;
    const int qBase = bn * BN + wn * 64;
#pragma unroll
    for (int i = 0; i < 4; ++i) {
#pragma unroll
        for (int r = 0; r < 4; ++r) {
            const int p = pBase + i * 16 + (l >> 4) * 4 + r;
            const float hp = -0.001f * (rr[p] - 0.1f);
#pragma unroll
            for (int j = 0; j < 4; ++j) {
                const int q = qBase + j * 16 + (l & 15);
                const size_t idx = (size_t)p * N + q;
                float v = fmaf(s, acc[i][j][r], Wold[idx] + hp);
                v = fminf(fmaxf(v, 0.f), 1.f);
                outF[idx] = v;
                outBf[idx] = f2bf(v);
            }
        }
    }
}

// ---------------------------------------------------------------------------
// BT-form bf16 MFMA GEMM (current = pre @ W^T), XOR-swizzled LDS.
// ---------------------------------------------------------------------------
template <int BM, int BN>
__global__ __launch_bounds__(256) void mfma_gemm_bt(
    const unsigned short* __restrict__ A,
    const unsigned short* __restrict__ Bm,
    int K, int N, float* __restrict__ outF)
{
    constexpr int BK = 32;
    constexpr int FI = BM / 32;
    constexpr int FJ = BN / 32;
    __shared__ unsigned short lA[BM * BK];
    __shared__ unsigned short lB[BN * BK];

    const int t = threadIdx.x;
    const int l = t & 63;
    const int w = t >> 6;
    const int wm = w >> 1, wn = w & 1;
    const int bm = blockIdx.y, bn = blockIdx.x;

    const int srow = t >> 2;
    const int sc = t & 3;
    const int gc = sc ^ ((srow >> 1) & 3);
    const int skc = sc * 8;
    const int gkc = gc * 8;

    floatx4 acc[FI][FJ] = {};

    for (int k0 = 0; k0 < K; k0 += BK) {
#pragma unroll
        for (int i = 0; i < BM / 64; ++i) {
            const unsigned short* gp =
                A + (size_t)(bm * BM + i * 64 + srow) * K + k0 + gkc;
            __builtin_amdgcn_global_load_lds(GLB_PTR(gp),
                LDS_PTR(&lA[(i * 64 + srow) * BK + skc]), 16, 0, 0);
        }
#pragma unroll
        for (int i = 0; i < BN / 64; ++i) {
            const unsigned short* gp =
                Bm + (size_t)(bn * BN + i * 64 + srow) * K + k0 + gkc;
            __builtin_amdgcn_global_load_lds(GLB_PTR(gp),
                LDS_PTR(&lB[(i * 64 + srow) * BK + skc]), 16, 0, 0);
        }
        __syncthreads();

        const int q = l >> 4;
        short8 af[FI], bf[FJ];
#pragma unroll
        for (int i = 0; i < FI; ++i) {
            int ra = wm * (BM / 2) + i * 16 + (l & 15);
            af[i] = *(const short8*)&lA[ra * BK + ((q ^ ((ra >> 1) & 3)) * 8)];
        }
#pragma unroll
        for (int j = 0; j < FJ; ++j) {
            int rb = wn * (BN / 2) + j * 16 + (l & 15);
            bf[j] = *(const short8*)&lB[rb * BK + ((q ^ ((rb >> 1) & 3)) * 8)];
        }
#pragma unroll
        for (int i = 0; i < FI; ++i)
#pragma unroll
            for (int j = 0; j < FJ; ++j)
                acc[i][j] = __builtin_amdgcn_mfma_f32_16x16x32_bf16(
                    af[i], bf[j], acc[i][j], 0, 0, 0);
        __syncthreads();
    }

    const int pBase = bm * BM + wm * (BM / 2);
    const int qBase = bn * BN + wn * (BN / 2);
#pragma unroll
    for (int i = 0; i < FI; ++i)
#pragma unroll
        for (int r = 0; r < 4; ++r) {
            const int p = pBase + i * 16 + (l >> 4) * 4 + r;
#pragma unroll
            for (int j = 0; j < FJ; ++j) {
                const int q = qBase + j * 16 + (l & 15);
                outF[(size_t)p * N + q] = acc[i][j][r];
            }
        }
}

// ---------------------------------------------------------------------------
extern "C" void kernel_launch(void* const* d_in, const int* in_sizes, int n_in,
                              void* d_out, int out_size, void* d_ws, size_t ws_size,
                              hipStream_t stream)
{
    const float* pre_spikes   = (const float*)d_in[0];
    const float* post_spikes  = (const float*)d_in[1];
    const float* weights      = (const float*)d_in[2];
    const float* pre_trace    = (const float*)d_in[3];
    const float* post_trace   = (const float*)d_in[4];
    const float* running_rate = (const float*)d_in[5];

    const int POST = in_sizes[5];
    const int PRE  = in_sizes[2] / POST;
    const int Bsz  = in_sizes[0] / PRE;
    const int K2   = 2 * Bsz;

    const size_t nCur   = (size_t)Bsz * POST;
    const size_t nW     = (size_t)POST * PRE;
    const size_t nPreT  = (size_t)Bsz * PRE;
    const size_t nPostT = (size_t)Bsz * POST;

    float* out_current    = (float*)d_out;
    float* out_weights    = out_current + nCur;
    float* out_pre_trace  = out_weights + nW;
    float* out_post_trace = out_pre_trace + nPreT;
    float* out_rate       = out_post_trace + nPostT;

    unsigned char* At     = (unsigned char*)d_ws;        // (POST x K2) fp8
    unsigned char* Bt     = At + (size_t)POST * K2;      // (PRE  x K2) fp8
    unsigned short* preBf = (unsigned short*)(Bt + (size_t)PRE * K2); // (B x PRE) bf16
    unsigned short* wBf   = preBf + nPreT;               // (POST x PRE) bf16

    const float dp = 0.95122942450071400910f;            // exp(-1/20)
    const float s  = dp * (0.01f / (float)Bsz);          // A+/-. * dp / B

    // 1) fused prep: traces + fp8 GEMM operands (one read per input)
    prep_post_kernel<<<dim3(POST / 64, Bsz / 64), 256, 0, stream>>>(
        post_spikes, post_trace, out_post_trace, At, POST, K2, Bsz, dp);
    prep_pre_kernel<<<dim3(PRE / 64, Bsz / 64), 256, 0, stream>>>(
        pre_spikes, pre_trace, out_pre_trace, Bt, preBf, PRE, K2, Bsz, dp);

    // 2) rate EMA
    rate_kernel<<<POST / 4, 256, 0, stream>>>(
        At, running_rate, out_rate, K2, Bsz);

    // 3) dw GEMM in MX-fp8 (M=POST, N=PRE, K=2B) + fused w/homeo/clip
    dw_fp8_kernel<<<dim3(PRE / 128, POST / 128), 256, 0, stream>>>(
        At, Bt, K2, PRE, s, weights, running_rate, out_weights, wBf);

    // 4) current GEMM bf16 (M=B, N=POST, K=PRE): pre_spikes @ new_w^T
    mfma_gemm_bt<64, 128><<<dim3(POST / 128, Bsz / 64), 256, 0, stream>>>(
        preBf, wBf, PRE, POST, out_current);
}